// Round 2
// baseline (2345.431 us; speedup 1.0000x reference)
//
#include <hip/hip_runtime.h>

#define NN 50000
#define EE 800000
#define DD 256
#define CC 4
#define BN_EPSF 1e-5f
#define MROWS 48
#define ZPAD 268  // f32 row stride: 1072B = 16B-aligned, 2-way-bank-safe for frag reads

typedef float v4f __attribute__((ext_vector_type(4)));
typedef float f32x4 __attribute__((ext_vector_type(4)));
typedef __bf16 bf16x8 __attribute__((ext_vector_type(8)));
typedef _Float16 h4 __attribute__((ext_vector_type(4)));

// ---------------- CSR build ----------------

__global__ void k_hist(const int* __restrict__ dst, int* __restrict__ cnt) {
  int e = blockIdx.x * 256 + threadIdx.x;
  if (e < EE) atomicAdd(&cnt[dst[e]], 1);
}

// single-block exclusive scan of cnt[0..NN) -> rp[0..NN], and cnt[i] := exclusive (cursor init)
__global__ void k_scan(int* __restrict__ cnt, int* __restrict__ rp) {
  __shared__ int wsums[16];
  __shared__ int sh_carry;
  __shared__ int sh_ctot;
  const int t = threadIdx.x;
  const int lane = t & 63;
  const int w = t >> 6;
  if (t == 0) sh_carry = 0;
  __syncthreads();
  for (int base = 0; base < NN; base += 1024) {
    int i = base + t;
    int v = (i < NN) ? cnt[i] : 0;
    int incl = v;
#pragma unroll
    for (int off = 1; off < 64; off <<= 1) {
      int u = __shfl_up(incl, off, 64);
      if (lane >= off) incl += u;
    }
    if (lane == 63) wsums[w] = incl;
    int cbase = sh_carry;
    __syncthreads();
    if (w == 0) {
      int s = (lane < 16) ? wsums[lane] : 0;
      int si = s;
#pragma unroll
      for (int off = 1; off < 16; off <<= 1) {
        int u = __shfl_up(si, off, 64);
        if (lane >= off) si += u;
      }
      if (lane < 16) wsums[lane] = si - s;  // exclusive wave offset
      if (lane == 15) sh_ctot = si;         // chunk total
    }
    __syncthreads();
    int excl = cbase + wsums[w] + (incl - v);
    if (i < NN) { rp[i] = excl; cnt[i] = excl; }
    __syncthreads();
    if (t == 0) sh_carry = cbase + sh_ctot;
    __syncthreads();
  }
  if (t == 0) rp[NN] = sh_carry;
}

__global__ void k_scatter(const int* __restrict__ src, const int* __restrict__ dst,
                          int* __restrict__ cur, int2* __restrict__ sse) {
  int e = blockIdx.x * 256 + threadIdx.x;
  if (e < EE) {
    int d = dst[e];
    int p = atomicAdd(&cur[d], 1);
    sse[p] = make_int2(src[e], e);
  }
}

// One wave per CSR slot p: ea16[p] = fp16(ea[se[p]]) (permute edge_attr into CSR
// order so per-pass ea reads are sequential), ss[p] = src.
__global__ __launch_bounds__(256) void k_permute(
    const int2* __restrict__ sse, const float* __restrict__ ea,
    int* __restrict__ ss, _Float16* __restrict__ ea16) {
  int p = (blockIdx.x * 256 + threadIdx.x) >> 6;
  int lane = threadIdx.x & 63;
  if (p >= EE) return;
  int2 d = sse[p];
  if (lane == 0) ss[p] = d.x;
  v4f v = __builtin_nontemporal_load(((const v4f*)(ea + (size_t)d.y * DD)) + lane);
  h4 h;
  h.x = (_Float16)v.x;
  h.y = (_Float16)v.y;
  h.z = (_Float16)v.z;
  h.w = (_Float16)v.w;
  __builtin_nontemporal_store(h, ((h4*)(ea16 + (size_t)p * DD)) + lane);
}

// ---------------- weight pre-format: frag-linear bf16 hi/lo ----------------
// layout per (c,mat): [half(2)][kk(8)][cg(16)][lane(64)][j(8)] bf16; 65536 bf16 per half.
// frag element: lane l holds W[kk*32 + 8*(l>>4) + j][cg*16 + (l&15)]  (B-operand layout)
__global__ void k_wfmt(const float* __restrict__ W1, const float* __restrict__ W2,
                       __bf16* __restrict__ wf, float* __restrict__ sc0,
                       float* __restrict__ sh0) {
  int b = blockIdx.x;  // 64 blocks = c(4) x mat(2) x kk(8)
  int c = b >> 4, mat = (b >> 3) & 1, kk = b & 7;
  const float* W = (mat ? W2 : W1) + (size_t)c * DD * DD;
  __bf16* base = wf + (size_t)(c * 2 + mat) * 2 * 65536;
  int t = threadIdx.x;
  int lane = t & 63, cq = t >> 6;
  int l4 = lane >> 4, l16 = lane & 15;
  if (b == 0) { sc0[t] = 1.f; sh0[t] = 0.f; }
#pragma unroll
  for (int ci = 0; ci < 4; ++ci) {
    int cg = cq * 4 + ci;
    bf16x8 hi, lo;
#pragma unroll
    for (int j = 0; j < 8; ++j) {
      float v = W[(size_t)(kk * 32 + l4 * 8 + j) * DD + cg * 16 + l16];
      __bf16 h = (__bf16)v;
      hi[j] = h;
      lo[j] = (__bf16)(v - (float)h);
    }
    size_t off = ((size_t)(kk * 16 + cg) * 64 + lane) * 8;
    *(bf16x8*)(base + off) = hi;
    *(bf16x8*)(base + 65536 + off) = lo;
  }
}

// ---------------- per-cluster kernels ----------------

__device__ __forceinline__ v4f relu4(v4f s) {
  s.x = fmaxf(s.x, 0.f); s.y = fmaxf(s.y, 0.f);
  s.z = fmaxf(s.z, 0.f); s.w = fmaxf(s.w, 0.f);
  return s;
}

// One wave per node: aggr[i] = sum over in-edges of relu(affine(y[src]) + ea16[p])
// ea16 is CSR-ordered (address linear in p); only the x-gather depends on ss[p].
__global__ __launch_bounds__(256) void k_aggregate(
    const float* __restrict__ ybase, const float* __restrict__ sc,
    const float* __restrict__ sh, const _Float16* __restrict__ ea16,
    const int* __restrict__ rp, const int* __restrict__ ss,
    float* __restrict__ aggr) {
  int node = (blockIdx.x * 256 + threadIdx.x) >> 6;
  int lane = threadIdx.x & 63;
  if (node >= NN) return;
  v4f sc4 = ((const v4f*)sc)[lane];
  v4f sh4 = ((const v4f*)sh)[lane];
  int beg = rp[node], end = rp[node + 1];
  v4f acc = {0.f, 0.f, 0.f, 0.f};
  int p = beg;
  for (; p + 4 <= end; p += 4) {
    int s0 = ss[p], s1 = ss[p + 1], s2 = ss[p + 2], s3 = ss[p + 3];
    h4 e0 = __builtin_nontemporal_load(((const h4*)(ea16 + (size_t)p * DD)) + lane);
    h4 e1 = __builtin_nontemporal_load(((const h4*)(ea16 + (size_t)(p + 1) * DD)) + lane);
    h4 e2 = __builtin_nontemporal_load(((const h4*)(ea16 + (size_t)(p + 2) * DD)) + lane);
    h4 e3 = __builtin_nontemporal_load(((const h4*)(ea16 + (size_t)(p + 3) * DD)) + lane);
    v4f x0 = ((const v4f*)(ybase + (size_t)s0 * DD))[lane];
    v4f x1 = ((const v4f*)(ybase + (size_t)s1 * DD))[lane];
    v4f x2 = ((const v4f*)(ybase + (size_t)s2 * DD))[lane];
    v4f x3 = ((const v4f*)(ybase + (size_t)s3 * DD))[lane];
    acc += relu4(sc4 * x0 + sh4 + __builtin_convertvector(e0, v4f));
    acc += relu4(sc4 * x1 + sh4 + __builtin_convertvector(e1, v4f));
    acc += relu4(sc4 * x2 + sh4 + __builtin_convertvector(e2, v4f));
    acc += relu4(sc4 * x3 + sh4 + __builtin_convertvector(e3, v4f));
  }
  for (; p < end; ++p) {
    int s0 = ss[p];
    h4 e0 = __builtin_nontemporal_load(((const h4*)(ea16 + (size_t)p * DD)) + lane);
    v4f x0 = ((const v4f*)(ybase + (size_t)s0 * DD))[lane];
    acc += relu4(sc4 * x0 + sh4 + __builtin_convertvector(e0, v4f));
  }
  ((v4f*)(aggr + (size_t)node * DD))[lane] = acc;
}

// split-bf16 MFMA GEMM: acc[3][4] (48 rows x 64 cols per wave) = bias + zb(48x256) @ W(256x256)
// W pre-formatted frag-linear hi/lo; A built on the fly from fp32 LDS rows.
__device__ __forceinline__ void gemm_frag(
    const float (*zb)[ZPAD], const __bf16* __restrict__ wf,
    const float* __restrict__ bias, f32x4 (&acc)[3][4], int w, int lane) {
  const int l4 = lane >> 4, l16 = lane & 15;
#pragma unroll
  for (int cg = 0; cg < 4; ++cg) {
    float bv = bias[w * 64 + cg * 16 + l16];
    f32x4 b4 = {bv, bv, bv, bv};
#pragma unroll
    for (int mg = 0; mg < 3; ++mg) acc[mg][cg] = b4;
  }
  for (int kk = 0; kk < 8; ++kk) {
    bf16x8 bh[4], bl[4];
#pragma unroll
    for (int cg = 0; cg < 4; ++cg) {
      const __bf16* p = wf + (((size_t)(kk * 16 + w * 4 + cg)) * 64 + lane) * 8;
      bh[cg] = *(const bf16x8*)p;
      bl[cg] = *(const bf16x8*)(p + 65536);
    }
#pragma unroll
    for (int mg = 0; mg < 3; ++mg) {
      const float* zp = &zb[mg * 16 + l16][kk * 32 + l4 * 8];
      float4 z0 = *(const float4*)zp;
      float4 z1 = *(const float4*)(zp + 4);
      float zv[8] = {z0.x, z0.y, z0.z, z0.w, z1.x, z1.y, z1.z, z1.w};
      bf16x8 ah, al;
#pragma unroll
      for (int j = 0; j < 8; ++j) {
        __bf16 h = (__bf16)zv[j];
        ah[j] = h;
        al[j] = (__bf16)(zv[j] - (float)h);
      }
#pragma unroll
      for (int cg = 0; cg < 4; ++cg) {
        acc[mg][cg] = __builtin_amdgcn_mfma_f32_16x16x32_bf16(al, bh[cg], acc[mg][cg], 0, 0, 0);
        acc[mg][cg] = __builtin_amdgcn_mfma_f32_16x16x32_bf16(ah, bl[cg], acc[mg][cg], 0, 0, 0);
        acc[mg][cg] = __builtin_amdgcn_mfma_f32_16x16x32_bf16(ah, bh[cg], acc[mg][cg], 0, 0, 0);
      }
    }
  }
}

// Fused: x=affine(ybase); z=(1+eps)x+aggr; t=relu(z@W1+b1); h=t@W2+b2;
// y=mask*h+x (in-place safe: block touches only its own rows); BN partial sums.
__global__ __launch_bounds__(256, 2) void k_mlp(
    const float* ybase, const float* __restrict__ sc, const float* __restrict__ sh,
    const float* __restrict__ aggr, float* yout,
    const __bf16* __restrict__ wf1, const __bf16* __restrict__ wf2,
    const float* __restrict__ b1g, const float* __restrict__ b2g,
    const float* __restrict__ maskc, const float* __restrict__ epsp,
    float* __restrict__ gsum, float* __restrict__ gsumsq) {
  __shared__ __align__(16) float zbuf[MROWS][ZPAD];
  __shared__ float ssum[DD];
  __shared__ float ssq[DD];
  const int t = threadIdx.x;
  const int lane = t & 63, w = t >> 6;
  const int l4 = lane >> 4, l16 = lane & 15;
  const int row0 = blockIdx.x * MROWS;
  ssum[t] = 0.f;
  ssq[t] = 0.f;
  const float ep = 1.0f + epsp[0];
  // stage z = ep*(sc*y+sh) + aggr, fp32, coalesced float4
#pragma unroll
  for (int i = 0; i < 12; ++i) {
    int f4 = t + 256 * i;          // 3072 float4 = 48x256
    int r = f4 >> 6, c4 = (f4 & 63) << 2;
    int row = row0 + r;
    float4 zv = make_float4(0.f, 0.f, 0.f, 0.f);
    if (row < NN) {
      float4 yv = *(const float4*)(ybase + (size_t)row * DD + c4);
      float4 av = *(const float4*)(aggr + (size_t)row * DD + c4);
      float4 scv = *(const float4*)(sc + c4);
      float4 shv = *(const float4*)(sh + c4);
      zv.x = fmaf(ep, fmaf(scv.x, yv.x, shv.x), av.x);
      zv.y = fmaf(ep, fmaf(scv.y, yv.y, shv.y), av.y);
      zv.z = fmaf(ep, fmaf(scv.z, yv.z, shv.z), av.z);
      zv.w = fmaf(ep, fmaf(scv.w, yv.w, shv.w), av.w);
    }
    *(float4*)&zbuf[r][c4] = zv;
  }
  __syncthreads();
  f32x4 acc[3][4];
  gemm_frag(zbuf, wf1, b1g, acc, w, lane);
  __syncthreads();  // all zbuf reads of GEMM1 done
  // t = relu(.) written back to zbuf (D layout: row=(l>>4)*4+r, col=l&15)
#pragma unroll
  for (int mg = 0; mg < 3; ++mg)
#pragma unroll
    for (int cg = 0; cg < 4; ++cg)
#pragma unroll
      for (int r = 0; r < 4; ++r)
        zbuf[mg * 16 + l4 * 4 + r][w * 64 + cg * 16 + l16] = fmaxf(acc[mg][cg][r], 0.f);
  __syncthreads();
  gemm_frag(zbuf, wf2, b2g, acc, w, lane);
  // epilogue
  float scv[4], shv[4], ps[4], pq[4];
#pragma unroll
  for (int cg = 0; cg < 4; ++cg) {
    int col = w * 64 + cg * 16 + l16;
    scv[cg] = sc[col];
    shv[cg] = sh[col];
    ps[cg] = 0.f;
    pq[cg] = 0.f;
  }
#pragma unroll
  for (int mg = 0; mg < 3; ++mg) {
#pragma unroll
    for (int r = 0; r < 4; ++r) {
      int row = row0 + mg * 16 + l4 * 4 + r;
      if (row < NN) {
        float m = maskc[row];
#pragma unroll
        for (int cg = 0; cg < 4; ++cg) {
          int col = w * 64 + cg * 16 + l16;
          float xv = fmaf(scv[cg], ybase[(size_t)row * DD + col], shv[cg]);
          float yv = fmaf(m, acc[mg][cg][r], xv);
          yout[(size_t)row * DD + col] = yv;
          ps[cg] += yv;
          pq[cg] += yv * yv;
        }
      }
    }
  }
#pragma unroll
  for (int cg = 0; cg < 4; ++cg) {
    atomicAdd(&ssum[w * 64 + cg * 16 + l16], ps[cg]);
    atomicAdd(&ssq[w * 64 + cg * 16 + l16], pq[cg]);
  }
  __syncthreads();
  atomicAdd(&gsum[t], ssum[t]);
  atomicAdd(&gsumsq[t], ssq[t]);
}

__global__ void k_bnstats(const float* __restrict__ gsum, const float* __restrict__ gsumsq,
                          const float* __restrict__ gamma_c, const float* __restrict__ beta_c,
                          float* __restrict__ scale, float* __restrict__ shift) {
  int d = threadIdx.x;
  const float inv_n = 1.0f / (float)NN;
  float mean = gsum[d] * inv_n;
  float var = fmaxf(gsumsq[d] * inv_n - mean * mean, 0.f);
  float sc = gamma_c[d] * rsqrtf(var + BN_EPSF);
  scale[d] = sc;
  shift[d] = fmaf(-mean, sc, beta_c[d]);
}

__global__ __launch_bounds__(256) void k_norm_final(
    const float* __restrict__ y, const float* __restrict__ scale,
    const float* __restrict__ shift, const float* __restrict__ x_in,
    float* __restrict__ out) {
  int idx = blockIdx.x * 256 + threadIdx.x;
  int c4 = idx & 63;
  float4 yv = ((const float4*)y)[idx];
  float4 sc = ((const float4*)scale)[c4];
  float4 sh = ((const float4*)shift)[c4];
  float4 xi = ((const float4*)x_in)[idx];
  float4 o;
  o.x = xi.x + fmaxf(fmaf(sc.x, yv.x, sh.x), 0.f);
  o.y = xi.y + fmaxf(fmaf(sc.y, yv.y, sh.y), 0.f);
  o.z = xi.z + fmaxf(fmaf(sc.z, yv.z, sh.z), 0.f);
  o.w = xi.w + fmaxf(fmaf(sc.w, yv.w, sh.w), 0.f);
  ((float4*)out)[idx] = o;
}

// ---------------- launch ----------------

extern "C" void kernel_launch(void* const* d_in, const int* in_sizes, int n_in,
                              void* d_out, int out_size, void* d_ws, size_t ws_size,
                              hipStream_t stream) {
  (void)in_sizes; (void)n_in; (void)out_size; (void)ws_size;
  const float* x_in  = (const float*)d_in[0];
  const int*   ei    = (const int*)d_in[1];
  const float* ea    = (const float*)d_in[2];
  const float* masks = (const float*)d_in[3];
  // d_in[4] = complement_masks: unused by the reference
  const float* W1    = (const float*)d_in[5];
  const float* b1    = (const float*)d_in[6];
  const float* W2    = (const float*)d_in[7];
  const float* b2    = (const float*)d_in[8];
  const float* eps   = (const float*)d_in[9];
  const float* gamma = (const float*)d_in[10];
  const float* beta  = (const float*)d_in[11];
  float* out = (float*)d_out;

  // workspace layout (all 16B-aligned); ~530 MB
  float* aggrb = (float*)d_ws;                        // NN*DD (aggregate output)
  float* yag   = aggrb + (size_t)NN * DD;             // NN*DD (pre-norm y, in-place per cluster)
  int2*  sse   = (int2*)(yag + (size_t)NN * DD);      // EE (src, edge) pairs (build only)
  int*   rp    = (int*)(sse + EE);                    // NN+1 (padded to 50016)
  int*   cnt   = rp + 50016;                          // NN (padded), also scatter cursor
  float* gsum  = (float*)(cnt + 50016);               // CC*DD
  float* gsumsq = gsum + CC * DD;                     // CC*DD
  float* scale = gsumsq + CC * DD;                    // DD
  float* shift = scale + DD;                          // DD
  float* sc0   = shift + DD;                          // DD (identity scale)
  float* sh0   = sc0 + DD;                            // DD (identity shift)
  __bf16* wfmt = (__bf16*)(sh0 + DD);                 // 4*2*2*65536 bf16 = 2 MB
  int*   ss    = (int*)(wfmt + (size_t)4 * 2 * 2 * 65536);  // EE (src per CSR slot)
  _Float16* ea16 = (_Float16*)(ss + EE);              // EE*DD fp16, CSR-ordered (410 MB)

  const int* src = ei;
  const int* dst = ei + EE;

  hipMemsetAsync(cnt, 0, NN * sizeof(int), stream);
  hipMemsetAsync(gsum, 0, 2 * CC * DD * sizeof(float), stream);

  k_wfmt<<<64, 256, 0, stream>>>(W1, W2, wfmt, sc0, sh0);
  k_hist<<<EE / 256, 256, 0, stream>>>(dst, cnt);
  k_scan<<<1, 1024, 0, stream>>>(cnt, rp);
  k_scatter<<<EE / 256, 256, 0, stream>>>(src, dst, cnt, sse);
  k_permute<<<EE / 4, 256, 0, stream>>>(sse, ea, ss, ea16);

  for (int c = 0; c < CC; ++c) {
    const float* yb  = (c == 0) ? x_in : yag;
    const float* scc = (c == 0) ? sc0 : scale;
    const float* shc = (c == 0) ? sh0 : shift;
    k_aggregate<<<(NN + 3) / 4, 256, 0, stream>>>(yb, scc, shc, ea16, rp, ss, aggrb);
    k_mlp<<<(NN + MROWS - 1) / MROWS, 256, 0, stream>>>(
        yb, scc, shc, aggrb, yag,
        wfmt + (size_t)(c * 2 + 0) * 2 * 65536,
        wfmt + (size_t)(c * 2 + 1) * 2 * 65536,
        b1 + (size_t)c * DD, b2 + (size_t)c * DD,
        masks + (size_t)c * NN, eps + c,
        gsum + c * DD, gsumsq + c * DD);
    k_bnstats<<<1, DD, 0, stream>>>(gsum + c * DD, gsumsq + c * DD,
                                    gamma + (size_t)c * DD, beta + (size_t)c * DD,
                                    scale, shift);
  }
  k_norm_final<<<(NN * DD / 4) / 256, 256, 0, stream>>>(yag, scale, shift, x_in, out);
}

// Round 3
// 2156.857 us; speedup vs baseline: 1.0874x; 1.0874x over previous
//
#include <hip/hip_runtime.h>

#define NN 50000
#define EE 800000
#define DD 256
#define CC 4
#define BN_EPSF 1e-5f
#define MROWS 48
#define ZPAD 268  // f32 row stride: 1072B = 16B-aligned, 2-way-bank-safe for frag reads

typedef float v4f __attribute__((ext_vector_type(4)));
typedef float f32x4 __attribute__((ext_vector_type(4)));
typedef __bf16 bf16x8 __attribute__((ext_vector_type(8)));
typedef _Float16 h4 __attribute__((ext_vector_type(4)));

// ---------------- CSR build ----------------

__global__ void k_hist(const int* __restrict__ dst, int* __restrict__ cnt) {
  int e = blockIdx.x * 256 + threadIdx.x;
  if (e < EE) atomicAdd(&cnt[dst[e]], 1);
}

// single-block exclusive scan of cnt[0..NN) -> rp[0..NN], and cnt[i] := exclusive (cursor init)
__global__ void k_scan(int* __restrict__ cnt, int* __restrict__ rp) {
  __shared__ int wsums[16];
  __shared__ int sh_carry;
  __shared__ int sh_ctot;
  const int t = threadIdx.x;
  const int lane = t & 63;
  const int w = t >> 6;
  if (t == 0) sh_carry = 0;
  __syncthreads();
  for (int base = 0; base < NN; base += 1024) {
    int i = base + t;
    int v = (i < NN) ? cnt[i] : 0;
    int incl = v;
#pragma unroll
    for (int off = 1; off < 64; off <<= 1) {
      int u = __shfl_up(incl, off, 64);
      if (lane >= off) incl += u;
    }
    if (lane == 63) wsums[w] = incl;
    int cbase = sh_carry;
    __syncthreads();
    if (w == 0) {
      int s = (lane < 16) ? wsums[lane] : 0;
      int si = s;
#pragma unroll
      for (int off = 1; off < 16; off <<= 1) {
        int u = __shfl_up(si, off, 64);
        if (lane >= off) si += u;
      }
      if (lane < 16) wsums[lane] = si - s;  // exclusive wave offset
      if (lane == 15) sh_ctot = si;         // chunk total
    }
    __syncthreads();
    int excl = cbase + wsums[w] + (incl - v);
    if (i < NN) { rp[i] = excl; cnt[i] = excl; }
    __syncthreads();
    if (t == 0) sh_carry = cbase + sh_ctot;
    __syncthreads();
  }
  if (t == 0) rp[NN] = sh_carry;
}

__global__ void k_scatter(const int* __restrict__ src, const int* __restrict__ dst,
                          int* __restrict__ cur, int2* __restrict__ sse) {
  int e = blockIdx.x * 256 + threadIdx.x;
  if (e < EE) {
    int d = dst[e];
    int p = atomicAdd(&cur[d], 1);
    sse[p] = make_int2(src[e], e);
  }
}

// One wave per CSR slot p: ea16[p] = fp16(ea[se[p]]) (permute edge_attr into CSR
// order so per-pass ea reads are sequential), ss[p] = src.
__global__ __launch_bounds__(256) void k_permute(
    const int2* __restrict__ sse, const float* __restrict__ ea,
    int* __restrict__ ss, _Float16* __restrict__ ea16) {
  int p = (blockIdx.x * 256 + threadIdx.x) >> 6;
  int lane = threadIdx.x & 63;
  if (p >= EE) return;
  int2 d = sse[p];
  if (lane == 0) ss[p] = d.x;
  v4f v = __builtin_nontemporal_load(((const v4f*)(ea + (size_t)d.y * DD)) + lane);
  h4 h;
  h.x = (_Float16)v.x;
  h.y = (_Float16)v.y;
  h.z = (_Float16)v.z;
  h.w = (_Float16)v.w;
  __builtin_nontemporal_store(h, ((h4*)(ea16 + (size_t)p * DD)) + lane);
}

// ---------------- weight pre-format: frag-linear bf16 hi/lo ----------------
// layout per (c,mat): [half(2)][kk(8)][cg(16)][lane(64)][j(8)] bf16; 65536 bf16 per half.
// frag element: lane l holds W[kk*32 + 8*(l>>4) + j][cg*16 + (l&15)]  (B-operand layout)
__global__ void k_wfmt(const float* __restrict__ W1, const float* __restrict__ W2,
                       __bf16* __restrict__ wf, float* __restrict__ sc0,
                       float* __restrict__ sh0) {
  int b = blockIdx.x;  // 64 blocks = c(4) x mat(2) x kk(8)
  int c = b >> 4, mat = (b >> 3) & 1, kk = b & 7;
  const float* W = (mat ? W2 : W1) + (size_t)c * DD * DD;
  __bf16* base = wf + (size_t)(c * 2 + mat) * 2 * 65536;
  int t = threadIdx.x;
  int lane = t & 63, cq = t >> 6;
  int l4 = lane >> 4, l16 = lane & 15;
  if (b == 0) { sc0[t] = 1.f; sh0[t] = 0.f; }
#pragma unroll
  for (int ci = 0; ci < 4; ++ci) {
    int cg = cq * 4 + ci;
    bf16x8 hi, lo;
#pragma unroll
    for (int j = 0; j < 8; ++j) {
      float v = W[(size_t)(kk * 32 + l4 * 8 + j) * DD + cg * 16 + l16];
      __bf16 h = (__bf16)v;
      hi[j] = h;
      lo[j] = (__bf16)(v - (float)h);
    }
    size_t off = ((size_t)(kk * 16 + cg) * 64 + lane) * 8;
    *(bf16x8*)(base + off) = hi;
    *(bf16x8*)(base + 65536 + off) = lo;
  }
}

// ---------------- per-cluster kernels ----------------

__device__ __forceinline__ v4f relu4(v4f s) {
  s.x = fmaxf(s.x, 0.f); s.y = fmaxf(s.y, 0.f);
  s.z = fmaxf(s.z, 0.f); s.w = fmaxf(s.w, 0.f);
  return s;
}

// x16[i] = fp16(scale*y[i] + shift) -- the gathered operand for k_aggregate
__global__ __launch_bounds__(256) void k_xcast(
    const float* __restrict__ y, const float* __restrict__ sc,
    const float* __restrict__ sh, _Float16* __restrict__ x16) {
  int idx = blockIdx.x * 256 + threadIdx.x;  // float4 index; grid = NN*DD/4/256
  int c4 = idx & 63;
  float4 yv = ((const float4*)y)[idx];
  float4 scv = ((const float4*)sc)[c4];
  float4 shv = ((const float4*)sh)[c4];
  h4 o;
  o.x = (_Float16)fmaf(scv.x, yv.x, shv.x);
  o.y = (_Float16)fmaf(scv.y, yv.y, shv.y);
  o.z = (_Float16)fmaf(scv.z, yv.z, shv.z);
  o.w = (_Float16)fmaf(scv.w, yv.w, shv.w);
  ((h4*)x16)[idx] = o;
}

// One wave per node: aggr[i] = sum over in-edges of relu(x16[src] + ea16[p]).
// ea16 is CSR-ordered (address linear in p); only the 512B x16-gather is random.
__global__ __launch_bounds__(256) void k_aggregate(
    const _Float16* __restrict__ x16, const _Float16* __restrict__ ea16,
    const int* __restrict__ rp, const int* __restrict__ ss,
    float* __restrict__ aggr) {
  int node = (blockIdx.x * 256 + threadIdx.x) >> 6;
  int lane = threadIdx.x & 63;
  if (node >= NN) return;
  int beg = rp[node], end = rp[node + 1];
  v4f acc = {0.f, 0.f, 0.f, 0.f};
  int p = beg;
  for (; p + 4 <= end; p += 4) {
    int s0 = ss[p], s1 = ss[p + 1], s2 = ss[p + 2], s3 = ss[p + 3];
    h4 e0 = __builtin_nontemporal_load(((const h4*)(ea16 + (size_t)p * DD)) + lane);
    h4 e1 = __builtin_nontemporal_load(((const h4*)(ea16 + (size_t)(p + 1) * DD)) + lane);
    h4 e2 = __builtin_nontemporal_load(((const h4*)(ea16 + (size_t)(p + 2) * DD)) + lane);
    h4 e3 = __builtin_nontemporal_load(((const h4*)(ea16 + (size_t)(p + 3) * DD)) + lane);
    h4 x0 = ((const h4*)(x16 + (size_t)s0 * DD))[lane];
    h4 x1 = ((const h4*)(x16 + (size_t)s1 * DD))[lane];
    h4 x2 = ((const h4*)(x16 + (size_t)s2 * DD))[lane];
    h4 x3 = ((const h4*)(x16 + (size_t)s3 * DD))[lane];
    acc += relu4(__builtin_convertvector(x0, v4f) + __builtin_convertvector(e0, v4f));
    acc += relu4(__builtin_convertvector(x1, v4f) + __builtin_convertvector(e1, v4f));
    acc += relu4(__builtin_convertvector(x2, v4f) + __builtin_convertvector(e2, v4f));
    acc += relu4(__builtin_convertvector(x3, v4f) + __builtin_convertvector(e3, v4f));
  }
  for (; p < end; ++p) {
    int s0 = ss[p];
    h4 e0 = __builtin_nontemporal_load(((const h4*)(ea16 + (size_t)p * DD)) + lane);
    h4 x0 = ((const h4*)(x16 + (size_t)s0 * DD))[lane];
    acc += relu4(__builtin_convertvector(x0, v4f) + __builtin_convertvector(e0, v4f));
  }
  ((v4f*)(aggr + (size_t)node * DD))[lane] = acc;
}

// split-bf16 MFMA GEMM: acc[3][4] (48 rows x 64 cols per wave) = bias + zb(48x256) @ W(256x256)
// W pre-formatted frag-linear hi/lo; A built on the fly from fp32 LDS rows.
__device__ __forceinline__ void gemm_frag(
    const float (*zb)[ZPAD], const __bf16* __restrict__ wf,
    const float* __restrict__ bias, f32x4 (&acc)[3][4], int w, int lane) {
  const int l4 = lane >> 4, l16 = lane & 15;
#pragma unroll
  for (int cg = 0; cg < 4; ++cg) {
    float bv = bias[w * 64 + cg * 16 + l16];
    f32x4 b4 = {bv, bv, bv, bv};
#pragma unroll
    for (int mg = 0; mg < 3; ++mg) acc[mg][cg] = b4;
  }
  for (int kk = 0; kk < 8; ++kk) {
    bf16x8 bh[4], bl[4];
#pragma unroll
    for (int cg = 0; cg < 4; ++cg) {
      const __bf16* p = wf + (((size_t)(kk * 16 + w * 4 + cg)) * 64 + lane) * 8;
      bh[cg] = *(const bf16x8*)p;
      bl[cg] = *(const bf16x8*)(p + 65536);
    }
#pragma unroll
    for (int mg = 0; mg < 3; ++mg) {
      const float* zp = &zb[mg * 16 + l16][kk * 32 + l4 * 8];
      float4 z0 = *(const float4*)zp;
      float4 z1 = *(const float4*)(zp + 4);
      float zv[8] = {z0.x, z0.y, z0.z, z0.w, z1.x, z1.y, z1.z, z1.w};
      bf16x8 ah, al;
#pragma unroll
      for (int j = 0; j < 8; ++j) {
        __bf16 h = (__bf16)zv[j];
        ah[j] = h;
        al[j] = (__bf16)(zv[j] - (float)h);
      }
#pragma unroll
      for (int cg = 0; cg < 4; ++cg) {
        acc[mg][cg] = __builtin_amdgcn_mfma_f32_16x16x32_bf16(al, bh[cg], acc[mg][cg], 0, 0, 0);
        acc[mg][cg] = __builtin_amdgcn_mfma_f32_16x16x32_bf16(ah, bl[cg], acc[mg][cg], 0, 0, 0);
        acc[mg][cg] = __builtin_amdgcn_mfma_f32_16x16x32_bf16(ah, bh[cg], acc[mg][cg], 0, 0, 0);
      }
    }
  }
}

// Fused: x=affine(ybase); z=(1+eps)x+aggr; t=relu(z@W1+b1); h=t@W2+b2;
// y=mask*h+x (in-place safe: block touches only its own rows); BN partial sums.
__global__ __launch_bounds__(256, 2) void k_mlp(
    const float* ybase, const float* __restrict__ sc, const float* __restrict__ sh,
    const float* __restrict__ aggr, float* yout,
    const __bf16* __restrict__ wf1, const __bf16* __restrict__ wf2,
    const float* __restrict__ b1g, const float* __restrict__ b2g,
    const float* __restrict__ maskc, const float* __restrict__ epsp,
    float* __restrict__ gsum, float* __restrict__ gsumsq) {
  __shared__ __align__(16) float zbuf[MROWS][ZPAD];
  __shared__ float ssum[DD];
  __shared__ float ssq[DD];
  const int t = threadIdx.x;
  const int lane = t & 63, w = t >> 6;
  const int l4 = lane >> 4, l16 = lane & 15;
  const int row0 = blockIdx.x * MROWS;
  ssum[t] = 0.f;
  ssq[t] = 0.f;
  const float ep = 1.0f + epsp[0];
  // stage z = ep*(sc*y+sh) + aggr, fp32, coalesced float4
#pragma unroll
  for (int i = 0; i < 12; ++i) {
    int f4 = t + 256 * i;          // 3072 float4 = 48x256
    int r = f4 >> 6, c4 = (f4 & 63) << 2;
    int row = row0 + r;
    float4 zv = make_float4(0.f, 0.f, 0.f, 0.f);
    if (row < NN) {
      float4 yv = *(const float4*)(ybase + (size_t)row * DD + c4);
      float4 av = *(const float4*)(aggr + (size_t)row * DD + c4);
      float4 scv = *(const float4*)(sc + c4);
      float4 shv = *(const float4*)(sh + c4);
      zv.x = fmaf(ep, fmaf(scv.x, yv.x, shv.x), av.x);
      zv.y = fmaf(ep, fmaf(scv.y, yv.y, shv.y), av.y);
      zv.z = fmaf(ep, fmaf(scv.z, yv.z, shv.z), av.z);
      zv.w = fmaf(ep, fmaf(scv.w, yv.w, shv.w), av.w);
    }
    *(float4*)&zbuf[r][c4] = zv;
  }
  __syncthreads();
  f32x4 acc[3][4];
  gemm_frag(zbuf, wf1, b1g, acc, w, lane);
  __syncthreads();  // all zbuf reads of GEMM1 done
  // t = relu(.) written back to zbuf (D layout: row=(l>>4)*4+r, col=l&15)
#pragma unroll
  for (int mg = 0; mg < 3; ++mg)
#pragma unroll
    for (int cg = 0; cg < 4; ++cg)
#pragma unroll
      for (int r = 0; r < 4; ++r)
        zbuf[mg * 16 + l4 * 4 + r][w * 64 + cg * 16 + l16] = fmaxf(acc[mg][cg][r], 0.f);
  __syncthreads();
  gemm_frag(zbuf, wf2, b2g, acc, w, lane);
  // epilogue
  float scv[4], shv[4], ps[4], pq[4];
#pragma unroll
  for (int cg = 0; cg < 4; ++cg) {
    int col = w * 64 + cg * 16 + l16;
    scv[cg] = sc[col];
    shv[cg] = sh[col];
    ps[cg] = 0.f;
    pq[cg] = 0.f;
  }
#pragma unroll
  for (int mg = 0; mg < 3; ++mg) {
#pragma unroll
    for (int r = 0; r < 4; ++r) {
      int row = row0 + mg * 16 + l4 * 4 + r;
      if (row < NN) {
        float m = maskc[row];
#pragma unroll
        for (int cg = 0; cg < 4; ++cg) {
          int col = w * 64 + cg * 16 + l16;
          float xv = fmaf(scv[cg], ybase[(size_t)row * DD + col], shv[cg]);
          float yv = fmaf(m, acc[mg][cg][r], xv);
          yout[(size_t)row * DD + col] = yv;
          ps[cg] += yv;
          pq[cg] += yv * yv;
        }
      }
    }
  }
#pragma unroll
  for (int cg = 0; cg < 4; ++cg) {
    atomicAdd(&ssum[w * 64 + cg * 16 + l16], ps[cg]);
    atomicAdd(&ssq[w * 64 + cg * 16 + l16], pq[cg]);
  }
  __syncthreads();
  atomicAdd(&gsum[t], ssum[t]);
  atomicAdd(&gsumsq[t], ssq[t]);
}

__global__ void k_bnstats(const float* __restrict__ gsum, const float* __restrict__ gsumsq,
                          const float* __restrict__ gamma_c, const float* __restrict__ beta_c,
                          float* __restrict__ scale, float* __restrict__ shift) {
  int d = threadIdx.x;
  const float inv_n = 1.0f / (float)NN;
  float mean = gsum[d] * inv_n;
  float var = fmaxf(gsumsq[d] * inv_n - mean * mean, 0.f);
  float sc = gamma_c[d] * rsqrtf(var + BN_EPSF);
  scale[d] = sc;
  shift[d] = fmaf(-mean, sc, beta_c[d]);
}

__global__ __launch_bounds__(256) void k_norm_final(
    const float* __restrict__ y, const float* __restrict__ scale,
    const float* __restrict__ shift, const float* __restrict__ x_in,
    float* __restrict__ out) {
  int idx = blockIdx.x * 256 + threadIdx.x;
  int c4 = idx & 63;
  float4 yv = ((const float4*)y)[idx];
  float4 sc = ((const float4*)scale)[c4];
  float4 sh = ((const float4*)shift)[c4];
  float4 xi = ((const float4*)x_in)[idx];
  float4 o;
  o.x = xi.x + fmaxf(fmaf(sc.x, yv.x, sh.x), 0.f);
  o.y = xi.y + fmaxf(fmaf(sc.y, yv.y, sh.y), 0.f);
  o.z = xi.z + fmaxf(fmaf(sc.z, yv.z, sh.z), 0.f);
  o.w = xi.w + fmaxf(fmaf(sc.w, yv.w, sh.w), 0.f);
  ((float4*)out)[idx] = o;
}

// ---------------- launch ----------------

extern "C" void kernel_launch(void* const* d_in, const int* in_sizes, int n_in,
                              void* d_out, int out_size, void* d_ws, size_t ws_size,
                              hipStream_t stream) {
  (void)in_sizes; (void)n_in; (void)out_size; (void)ws_size;
  const float* x_in  = (const float*)d_in[0];
  const int*   ei    = (const int*)d_in[1];
  const float* ea    = (const float*)d_in[2];
  const float* masks = (const float*)d_in[3];
  // d_in[4] = complement_masks: unused by the reference
  const float* W1    = (const float*)d_in[5];
  const float* b1    = (const float*)d_in[6];
  const float* W2    = (const float*)d_in[7];
  const float* b2    = (const float*)d_in[8];
  const float* eps   = (const float*)d_in[9];
  const float* gamma = (const float*)d_in[10];
  const float* beta  = (const float*)d_in[11];
  float* out = (float*)d_out;

  // workspace layout (all 16B-aligned); ~560 MB
  float* aggrb = (float*)d_ws;                        // NN*DD (aggregate output)
  float* yag   = aggrb + (size_t)NN * DD;             // NN*DD (pre-norm y, in-place per cluster)
  int2*  sse   = (int2*)(yag + (size_t)NN * DD);      // EE (src, edge) pairs (build only)
  int*   rp    = (int*)(sse + EE);                    // NN+1 (padded to 50016)
  int*   cnt   = rp + 50016;                          // NN (padded), also scatter cursor
  float* gsum  = (float*)(cnt + 50016);               // CC*DD
  float* gsumsq = gsum + CC * DD;                     // CC*DD
  float* scale = gsumsq + CC * DD;                    // DD
  float* shift = scale + DD;                          // DD
  float* sc0   = shift + DD;                          // DD (identity scale)
  float* sh0   = sc0 + DD;                            // DD (identity shift)
  __bf16* wfmt = (__bf16*)(sh0 + DD);                 // 4*2*2*65536 bf16 = 2 MB
  int*   ss    = (int*)(wfmt + (size_t)4 * 2 * 2 * 65536);  // EE (src per CSR slot)
  _Float16* ea16 = (_Float16*)(ss + EE);              // EE*DD fp16, CSR-ordered (410 MB)
  _Float16* x16  = ea16 + (size_t)EE * DD;            // NN*DD fp16 (gathered operand, 26 MB)

  const int* src = ei;
  const int* dst = ei + EE;

  hipMemsetAsync(cnt, 0, NN * sizeof(int), stream);
  hipMemsetAsync(gsum, 0, 2 * CC * DD * sizeof(float), stream);

  k_wfmt<<<64, 256, 0, stream>>>(W1, W2, wfmt, sc0, sh0);
  k_hist<<<EE / 256, 256, 0, stream>>>(dst, cnt);
  k_scan<<<1, 1024, 0, stream>>>(cnt, rp);
  k_scatter<<<EE / 256, 256, 0, stream>>>(src, dst, cnt, sse);
  k_permute<<<EE / 4, 256, 0, stream>>>(sse, ea, ss, ea16);
  k_xcast<<<NN * DD / 4 / 256, 256, 0, stream>>>(x_in, sc0, sh0, x16);

  for (int c = 0; c < CC; ++c) {
    const float* yb  = (c == 0) ? x_in : yag;
    const float* scc = (c == 0) ? sc0 : scale;
    const float* shc = (c == 0) ? sh0 : shift;
    k_aggregate<<<(NN + 3) / 4, 256, 0, stream>>>(x16, ea16, rp, ss, aggrb);
    k_mlp<<<(NN + MROWS - 1) / MROWS, 256, 0, stream>>>(
        yb, scc, shc, aggrb, yag,
        wfmt + (size_t)(c * 2 + 0) * 2 * 65536,
        wfmt + (size_t)(c * 2 + 1) * 2 * 65536,
        b1 + (size_t)c * DD, b2 + (size_t)c * DD,
        masks + (size_t)c * NN, eps + c,
        gsum + c * DD, gsumsq + c * DD);
    k_bnstats<<<1, DD, 0, stream>>>(gsum + c * DD, gsumsq + c * DD,
                                    gamma + (size_t)c * DD, beta + (size_t)c * DD,
                                    scale, shift);
    if (c < CC - 1)
      k_xcast<<<NN * DD / 4 / 256, 256, 0, stream>>>(yag, scale, shift, x16);
  }
  k_norm_final<<<(NN * DD / 4) / 256, 256, 0, stream>>>(yag, scale, shift, x_in, out);
}

// Round 4
// 1855.937 us; speedup vs baseline: 1.2637x; 1.1621x over previous
//
#include <hip/hip_runtime.h>

#define NN 50000
#define EE 800000
#define DD 256
#define CC 4
#define BN_EPSF 1e-5f
#define MROWS 48
#define ZPAD 268  // f32 row stride: 1072B = 16B-aligned, 2-way-bank-safe for frag reads

typedef float v4f __attribute__((ext_vector_type(4)));
typedef float f32x4 __attribute__((ext_vector_type(4)));
typedef __bf16 bf16x8 __attribute__((ext_vector_type(8)));
typedef _Float16 h4 __attribute__((ext_vector_type(4)));

// ---------------- CSR build ----------------

__global__ void k_hist(const int* __restrict__ dst, int* __restrict__ cnt) {
  int e = blockIdx.x * 256 + threadIdx.x;
  if (e < EE) atomicAdd(&cnt[dst[e]], 1);
}

// single-block exclusive scan of cnt[0..NN) -> rp[0..NN], and cnt[i] := exclusive (cursor init)
__global__ void k_scan(int* __restrict__ cnt, int* __restrict__ rp) {
  __shared__ int wsums[16];
  __shared__ int sh_carry;
  __shared__ int sh_ctot;
  const int t = threadIdx.x;
  const int lane = t & 63;
  const int w = t >> 6;
  if (t == 0) sh_carry = 0;
  __syncthreads();
  for (int base = 0; base < NN; base += 1024) {
    int i = base + t;
    int v = (i < NN) ? cnt[i] : 0;
    int incl = v;
#pragma unroll
    for (int off = 1; off < 64; off <<= 1) {
      int u = __shfl_up(incl, off, 64);
      if (lane >= off) incl += u;
    }
    if (lane == 63) wsums[w] = incl;
    int cbase = sh_carry;
    __syncthreads();
    if (w == 0) {
      int s = (lane < 16) ? wsums[lane] : 0;
      int si = s;
#pragma unroll
      for (int off = 1; off < 16; off <<= 1) {
        int u = __shfl_up(si, off, 64);
        if (lane >= off) si += u;
      }
      if (lane < 16) wsums[lane] = si - s;  // exclusive wave offset
      if (lane == 15) sh_ctot = si;         // chunk total
    }
    __syncthreads();
    int excl = cbase + wsums[w] + (incl - v);
    if (i < NN) { rp[i] = excl; cnt[i] = excl; }
    __syncthreads();
    if (t == 0) sh_carry = cbase + sh_ctot;
    __syncthreads();
  }
  if (t == 0) rp[NN] = sh_carry;
}

__global__ void k_scatter(const int* __restrict__ src, const int* __restrict__ dst,
                          int* __restrict__ cur, int2* __restrict__ sse) {
  int e = blockIdx.x * 256 + threadIdx.x;
  if (e < EE) {
    int d = dst[e];
    int p = atomicAdd(&cur[d], 1);
    sse[p] = make_int2(src[e], e);
  }
}

// per-node cluster id -> compacted per-cluster node lists; pcl[i] = (c<<28)|listpos
__global__ void k_compact(const float* __restrict__ masks, int* __restrict__ ncount,
                          int* __restrict__ nlist, int* __restrict__ pcl) {
  int i = blockIdx.x * 256 + threadIdx.x;
  if (i >= NN) return;
  int c = 0;
#pragma unroll
  for (int k = 1; k < CC; ++k)
    if (masks[(size_t)k * NN + i] > 0.5f) c = k;
  int li = atomicAdd(&ncount[c], 1);
  nlist[c * NN + li] = i;
  pcl[i] = (c << 28) | li;
}

// ---------------- weight pre-format: frag-linear bf16 hi/lo ----------------
// layout per (c,mat): [half(2)][kk(8)][cg(16)][lane(64)][j(8)] bf16; 65536 bf16 per half.
// frag element: lane l holds W[kk*32 + 8*(l>>4) + j][cg*16 + (l&15)]  (B-operand layout)
__global__ void k_wfmt(const float* __restrict__ W1, const float* __restrict__ W2,
                       __bf16* __restrict__ wf) {
  int b = blockIdx.x;  // 64 blocks = c(4) x mat(2) x kk(8)
  int c = b >> 4, mat = (b >> 3) & 1, kk = b & 7;
  const float* W = (mat ? W2 : W1) + (size_t)c * DD * DD;
  __bf16* base = wf + (size_t)(c * 2 + mat) * 2 * 65536;
  int t = threadIdx.x;
  int lane = t & 63, cq = t >> 6;
  int l4 = lane >> 4, l16 = lane & 15;
#pragma unroll
  for (int ci = 0; ci < 4; ++ci) {
    int cg = cq * 4 + ci;
    bf16x8 hi, lo;
#pragma unroll
    for (int j = 0; j < 8; ++j) {
      float v = W[(size_t)(kk * 32 + l4 * 8 + j) * DD + cg * 16 + l16];
      __bf16 h = (__bf16)v;
      hi[j] = h;
      lo[j] = (__bf16)(v - (float)h);
    }
    size_t off = ((size_t)(kk * 16 + cg) * 64 + lane) * 8;
    *(bf16x8*)(base + off) = hi;
    *(bf16x8*)(base + 65536 + off) = lo;
  }
}

// ---------------- helpers ----------------

__device__ __forceinline__ v4f relu4(v4f s) {
  s.x = fmaxf(s.x, 0.f); s.y = fmaxf(s.y, 0.f);
  s.z = fmaxf(s.z, 0.f); s.w = fmaxf(s.w, 0.f);
  return s;
}

// prologue: x16 = fp16(x_in); accumulate per-dim sum/sumsq of x_0 into g1/g2
__global__ __launch_bounds__(256) void k_prep(const float* __restrict__ xin,
                                              _Float16* __restrict__ x16,
                                              float* __restrict__ g1,
                                              float* __restrict__ g2) {
  __shared__ float s1[DD], s2[DD];
  const int t = threadIdx.x;
  s1[t] = 0.f;
  s2[t] = 0.f;
  float ps[4] = {0.f, 0.f, 0.f, 0.f};
  float pq[4] = {0.f, 0.f, 0.f, 0.f};
  const int stride = gridDim.x * 256;
  for (int idx = blockIdx.x * 256 + t; idx < NN * DD / 4; idx += stride) {
    float4 v = ((const float4*)xin)[idx];
    h4 o;
    o.x = (_Float16)v.x; o.y = (_Float16)v.y;
    o.z = (_Float16)v.z; o.w = (_Float16)v.w;
    ((h4*)x16)[idx] = o;
    ps[0] += v.x; ps[1] += v.y; ps[2] += v.z; ps[3] += v.w;
    pq[0] += v.x * v.x; pq[1] += v.y * v.y; pq[2] += v.z * v.z; pq[3] += v.w * v.w;
  }
  __syncthreads();  // s zero visible
  const int c4 = (t & 63) << 2;  // stride % 64 == 0 so dim set is fixed per thread
#pragma unroll
  for (int j = 0; j < 4; ++j) {
    atomicAdd(&s1[c4 + j], ps[j]);
    atomicAdd(&s2[c4 + j], pq[j]);
  }
  __syncthreads();
  atomicAdd(&g1[t], s1[t]);
  atomicAdd(&g2[t], s2[t]);
}

// One wave per masked node (list position li): aggrc[li] = sum_{in-edges} relu(x16[src] + ea[e])
__global__ __launch_bounds__(256) void k_aggregate_m(
    const _Float16* __restrict__ x16, const float* __restrict__ ea,
    const int* __restrict__ rp, const int2* __restrict__ sse,
    const int* __restrict__ nlist_c, const int* __restrict__ ncnt_c,
    float* __restrict__ aggrc) {
  int li = (blockIdx.x * 256 + threadIdx.x) >> 6;
  int lane = threadIdx.x & 63;
  if (li >= *ncnt_c) return;
  int node = nlist_c[li];
  int beg = rp[node], end = rp[node + 1];
  v4f acc = {0.f, 0.f, 0.f, 0.f};
  int p = beg;
  for (; p + 4 <= end; p += 4) {
    int2 d0 = sse[p];
    int2 d1 = sse[p + 1];
    int2 d2 = sse[p + 2];
    int2 d3 = sse[p + 3];
    v4f a0 = __builtin_nontemporal_load(((const v4f*)(ea + (size_t)d0.y * DD)) + lane);
    v4f a1 = __builtin_nontemporal_load(((const v4f*)(ea + (size_t)d1.y * DD)) + lane);
    v4f a2 = __builtin_nontemporal_load(((const v4f*)(ea + (size_t)d2.y * DD)) + lane);
    v4f a3 = __builtin_nontemporal_load(((const v4f*)(ea + (size_t)d3.y * DD)) + lane);
    h4 x0 = ((const h4*)(x16 + (size_t)d0.x * DD))[lane];
    h4 x1 = ((const h4*)(x16 + (size_t)d1.x * DD))[lane];
    h4 x2 = ((const h4*)(x16 + (size_t)d2.x * DD))[lane];
    h4 x3 = ((const h4*)(x16 + (size_t)d3.x * DD))[lane];
    acc += relu4(__builtin_convertvector(x0, v4f) + a0);
    acc += relu4(__builtin_convertvector(x1, v4f) + a1);
    acc += relu4(__builtin_convertvector(x2, v4f) + a2);
    acc += relu4(__builtin_convertvector(x3, v4f) + a3);
  }
  for (; p < end; ++p) {
    int2 d0 = sse[p];
    v4f a0 = __builtin_nontemporal_load(((const v4f*)(ea + (size_t)d0.y * DD)) + lane);
    h4 x0 = ((const h4*)(x16 + (size_t)d0.x * DD))[lane];
    acc += relu4(__builtin_convertvector(x0, v4f) + a0);
  }
  ((v4f*)(aggrc + (size_t)li * DD))[lane] = acc;
}

// split-bf16 MFMA GEMM: acc[3][4] (48 rows x 64 cols per wave) = bias + zb(48x256) @ W(256x256)
__device__ __forceinline__ void gemm_frag(
    const float (*zb)[ZPAD], const __bf16* __restrict__ wf,
    const float* __restrict__ bias, f32x4 (&acc)[3][4], int w, int lane) {
  const int l4 = lane >> 4, l16 = lane & 15;
#pragma unroll
  for (int cg = 0; cg < 4; ++cg) {
    float bv = bias[w * 64 + cg * 16 + l16];
    f32x4 b4 = {bv, bv, bv, bv};
#pragma unroll
    for (int mg = 0; mg < 3; ++mg) acc[mg][cg] = b4;
  }
  for (int kk = 0; kk < 8; ++kk) {
    bf16x8 bh[4], bl[4];
#pragma unroll
    for (int cg = 0; cg < 4; ++cg) {
      const __bf16* p = wf + (((size_t)(kk * 16 + w * 4 + cg)) * 64 + lane) * 8;
      bh[cg] = *(const bf16x8*)p;
      bl[cg] = *(const bf16x8*)(p + 65536);
    }
#pragma unroll
    for (int mg = 0; mg < 3; ++mg) {
      const float* zp = &zb[mg * 16 + l16][kk * 32 + l4 * 8];
      float4 z0 = *(const float4*)zp;
      float4 z1 = *(const float4*)(zp + 4);
      float zv[8] = {z0.x, z0.y, z0.z, z0.w, z1.x, z1.y, z1.z, z1.w};
      bf16x8 ah, al;
#pragma unroll
      for (int j = 0; j < 8; ++j) {
        __bf16 h = (__bf16)zv[j];
        ah[j] = h;
        al[j] = (__bf16)(zv[j] - (float)h);
      }
#pragma unroll
      for (int cg = 0; cg < 4; ++cg) {
        acc[mg][cg] = __builtin_amdgcn_mfma_f32_16x16x32_bf16(al, bh[cg], acc[mg][cg], 0, 0, 0);
        acc[mg][cg] = __builtin_amdgcn_mfma_f32_16x16x32_bf16(ah, bl[cg], acc[mg][cg], 0, 0, 0);
        acc[mg][cg] = __builtin_amdgcn_mfma_f32_16x16x32_bf16(ah, bh[cg], acc[mg][cg], 0, 0, 0);
      }
    }
  }
}

// Masked-rows MLP: z=(1+eps)x+aggr; t=relu(z@W1+b1); h=t@W2+b2; y=h+x (mask==1 here);
// writes ycomp[li]; accumulates BN-stat corrections sum(y-x), sum(y^2-x^2).
__global__ __launch_bounds__(256, 2) void k_mlp_m(
    const float* __restrict__ xc, const float* __restrict__ aggrc,
    float* __restrict__ ycomp,
    const __bf16* __restrict__ wf1, const __bf16* __restrict__ wf2,
    const float* __restrict__ b1g, const float* __restrict__ b2g,
    const int* __restrict__ nlist_c, const int* __restrict__ ncnt_c,
    const float* __restrict__ epsp,
    float* __restrict__ gd1, float* __restrict__ gd2) {
  __shared__ __align__(16) float zbuf[MROWS][ZPAD];
  __shared__ float ssum[DD];
  __shared__ float ssq[DD];
  __shared__ int nls[MROWS];
  const int t = threadIdx.x;
  const int lane = t & 63, w = t >> 6;
  const int l4 = lane >> 4, l16 = lane & 15;
  const int ncnt = *ncnt_c;
  const int li0 = blockIdx.x * MROWS;
  if (li0 >= ncnt) return;
  if (t < MROWS) nls[t] = (li0 + t < ncnt) ? nlist_c[li0 + t] : -1;
  ssum[t] = 0.f;
  ssq[t] = 0.f;
  const float ep = 1.0f + epsp[0];
  __syncthreads();
  // stage z = ep*x + aggr (fp32, coalesced float4)
#pragma unroll
  for (int i = 0; i < 12; ++i) {
    int f4 = t + 256 * i;  // 3072 float4 = 48x256
    int r = f4 >> 6, c4 = (f4 & 63) << 2;
    int nid = nls[r];
    float4 zv = make_float4(0.f, 0.f, 0.f, 0.f);
    if (nid >= 0) {
      float4 xv = *(const float4*)(xc + (size_t)nid * DD + c4);
      float4 av = *(const float4*)(aggrc + (size_t)(li0 + r) * DD + c4);
      zv.x = fmaf(ep, xv.x, av.x);
      zv.y = fmaf(ep, xv.y, av.y);
      zv.z = fmaf(ep, xv.z, av.z);
      zv.w = fmaf(ep, xv.w, av.w);
    }
    *(float4*)&zbuf[r][c4] = zv;
  }
  __syncthreads();
  f32x4 acc[3][4];
  gemm_frag(zbuf, wf1, b1g, acc, w, lane);
  __syncthreads();  // all zbuf reads of GEMM1 done
  // t = relu(.) written back to zbuf (D layout: row=(l>>4)*4+r, col=l&15)
#pragma unroll
  for (int mg = 0; mg < 3; ++mg)
#pragma unroll
    for (int cg = 0; cg < 4; ++cg)
#pragma unroll
      for (int r = 0; r < 4; ++r)
        zbuf[mg * 16 + l4 * 4 + r][w * 64 + cg * 16 + l16] = fmaxf(acc[mg][cg][r], 0.f);
  __syncthreads();
  f32x4 acc2[3][4];
  gemm_frag(zbuf, wf2, b2g, acc2, w, lane);
  // epilogue: y = h + x; corrections sum(h), sum(y^2 - x^2)
  float ps[4], pq[4];
#pragma unroll
  for (int cg = 0; cg < 4; ++cg) { ps[cg] = 0.f; pq[cg] = 0.f; }
#pragma unroll
  for (int mg = 0; mg < 3; ++mg) {
#pragma unroll
    for (int r = 0; r < 4; ++r) {
      int rb = mg * 16 + l4 * 4 + r;
      int nid = nls[rb];
      if (nid >= 0) {
#pragma unroll
        for (int cg = 0; cg < 4; ++cg) {
          int col = w * 64 + cg * 16 + l16;
          float xv = xc[(size_t)nid * DD + col];
          float hv = acc2[mg][cg][r];
          float yv = xv + hv;
          ycomp[(size_t)(li0 + rb) * DD + col] = yv;
          ps[cg] += hv;
          pq[cg] += yv * yv - xv * xv;
        }
      }
    }
  }
#pragma unroll
  for (int cg = 0; cg < 4; ++cg) {
    atomicAdd(&ssum[w * 64 + cg * 16 + l16], ps[cg]);
    atomicAdd(&ssq[w * 64 + cg * 16 + l16], pq[cg]);
  }
  __syncthreads();
  atomicAdd(&gd1[t], ssum[t]);
  atomicAdd(&gd2[t], ssq[t]);
}

__global__ void k_bnstats_m(const float* __restrict__ g1, const float* __restrict__ g2,
                            const float* __restrict__ gd1, const float* __restrict__ gd2,
                            const float* __restrict__ gamma_c, const float* __restrict__ beta_c,
                            float* __restrict__ scale, float* __restrict__ shift) {
  int d = threadIdx.x;
  const float inv_n = 1.0f / (float)NN;
  float mean = (g1[d] + gd1[d]) * inv_n;
  float var = fmaxf((g2[d] + gd2[d]) * inv_n - mean * mean, 0.f);
  float sc = gamma_c[d] * rsqrtf(var + BN_EPSF);
  scale[d] = sc;
  shift[d] = fmaf(-mean, sc, beta_c[d]);
}

// Full-stream BN apply: y_i = x_i (+ h if node in cluster c); x_next = sc*y + sh.
// Non-final: write x_next (fp32 + fp16), accumulate sums of x_next for next pass.
// Final: out = x_in + relu(x_next).
__global__ __launch_bounds__(256) void k_bnapply(
    const float* __restrict__ xc, const float* __restrict__ ycomp,
    const int* __restrict__ pcl, const float* __restrict__ scale,
    const float* __restrict__ shift, float* __restrict__ xnew,
    _Float16* __restrict__ x16, float* __restrict__ g1, float* __restrict__ g2,
    const float* __restrict__ xin, float* __restrict__ outp,
    int cidx, int final) {
  __shared__ float s1[DD];
  __shared__ float s2[DD];
  const int t = threadIdx.x;
  const int lane = t & 63;
  s1[t] = 0.f;
  s2[t] = 0.f;
  v4f sc4 = ((const v4f*)scale)[lane];
  v4f sh4 = ((const v4f*)shift)[lane];
  float ps[4] = {0.f, 0.f, 0.f, 0.f};
  float pq[4] = {0.f, 0.f, 0.f, 0.f};
  const int wid0 = (blockIdx.x * 256 + t) >> 6;
  const int wstride = gridDim.x * 4;
  for (int i = wid0; i < NN; i += wstride) {
    v4f xv = ((const v4f*)(xc + (size_t)i * DD))[lane];
    int pc = pcl[i];
    v4f yv = xv;
    if ((pc >> 28) == cidx) {
      int li = pc & 0x0FFFFFFF;
      yv = ((const v4f*)(ycomp + (size_t)li * DD))[lane];
    }
    v4f xn = sc4 * yv + sh4;
    if (final) {
      v4f xi = ((const v4f*)(xin + (size_t)i * DD))[lane];
      v4f o = xi + relu4(xn);
      ((v4f*)(outp + (size_t)i * DD))[lane] = o;
    } else {
      ((v4f*)(xnew + (size_t)i * DD))[lane] = xn;
      h4 h;
      h.x = (_Float16)xn.x; h.y = (_Float16)xn.y;
      h.z = (_Float16)xn.z; h.w = (_Float16)xn.w;
      ((h4*)(x16 + (size_t)i * DD))[lane] = h;
      ps[0] += xn.x; ps[1] += xn.y; ps[2] += xn.z; ps[3] += xn.w;
      pq[0] += xn.x * xn.x; pq[1] += xn.y * xn.y;
      pq[2] += xn.z * xn.z; pq[3] += xn.w * xn.w;
    }
  }
  if (!final) {
    __syncthreads();
    const int c4 = lane << 2;
#pragma unroll
    for (int j = 0; j < 4; ++j) {
      atomicAdd(&s1[c4 + j], ps[j]);
      atomicAdd(&s2[c4 + j], pq[j]);
    }
    __syncthreads();
    atomicAdd(&g1[t], s1[t]);
    atomicAdd(&g2[t], s2[t]);
  }
}

// ---------------- launch ----------------

extern "C" void kernel_launch(void* const* d_in, const int* in_sizes, int n_in,
                              void* d_out, int out_size, void* d_ws, size_t ws_size,
                              hipStream_t stream) {
  (void)in_sizes; (void)n_in; (void)out_size; (void)ws_size;
  const float* x_in  = (const float*)d_in[0];
  const int*   ei    = (const int*)d_in[1];
  const float* ea    = (const float*)d_in[2];
  const float* masks = (const float*)d_in[3];
  // d_in[4] = complement_masks: unused by the reference
  const float* W1    = (const float*)d_in[5];
  const float* b1    = (const float*)d_in[6];
  const float* W2    = (const float*)d_in[7];
  const float* b2    = (const float*)d_in[8];
  const float* eps   = (const float*)d_in[9];
  const float* gamma = (const float*)d_in[10];
  const float* beta  = (const float*)d_in[11];
  float* out = (float*)d_out;

  // workspace layout (all 16B-aligned); ~200 MB
  float* xcur  = (float*)d_ws;                        // NN*DD (x_c, c>=1)
  float* ycomp = xcur + (size_t)NN * DD;              // NN*DD (compact y rows of masked nodes)
  float* aggrc = ycomp + (size_t)NN * DD;             // NN*DD (compact aggregates)
  _Float16* x16 = (_Float16*)(aggrc + (size_t)NN * DD);  // NN*DD fp16 (gather operand)
  int2*  sse   = (int2*)(x16 + (size_t)NN * DD);      // EE (src, edge) per CSR slot
  int*   rp    = (int*)(sse + EE);                    // NN+1 (padded to 50016)
  int*   cnt   = rp + 50016;                          // NN (padded), also scatter cursor
  int*   nlist = cnt + 50016;                         // CC*NN (compacted node lists)
  int*   pcl   = nlist + CC * NN;                     // NN packed (c<<28)|listpos
  int*   ncount = pcl + NN;                           // CC (padded to 16)
  float* gx1   = (float*)(ncount + 16);               // 5*DD  sum(x_c)
  float* gx2   = gx1 + 5 * DD;                        // 5*DD  sum(x_c^2)
  float* gd1   = gx2 + 5 * DD;                        // CC*DD corrections sum(y-x)
  float* gd2   = gd1 + CC * DD;                       // CC*DD corrections sum(y^2-x^2)
  float* scale = gd2 + CC * DD;                       // DD
  float* shift = scale + DD;                          // DD
  __bf16* wfmt = (__bf16*)(shift + DD);               // 4*2*2*65536 bf16 = 2 MB

  const int* src = ei;
  const int* dst = ei + EE;

  hipMemsetAsync(cnt, 0, NN * sizeof(int), stream);
  hipMemsetAsync(ncount, 0, 16 * sizeof(int), stream);
  hipMemsetAsync(gx1, 0, (5 + 5 + CC + CC) * DD * sizeof(float), stream);

  k_wfmt<<<64, 256, 0, stream>>>(W1, W2, wfmt);
  k_hist<<<EE / 256, 256, 0, stream>>>(dst, cnt);
  k_scan<<<1, 1024, 0, stream>>>(cnt, rp);
  k_scatter<<<EE / 256, 256, 0, stream>>>(src, dst, cnt, sse);
  k_compact<<<(NN + 255) / 256, 256, 0, stream>>>(masks, ncount, nlist, pcl);
  k_prep<<<1024, 256, 0, stream>>>(x_in, x16, gx1, gx2);

  for (int c = 0; c < CC; ++c) {
    const float* xc = (c == 0) ? x_in : xcur;
    k_aggregate_m<<<(NN * 64 + 255) / 256, 256, 0, stream>>>(
        x16, ea, rp, sse, nlist + c * NN, ncount + c, aggrc);
    k_mlp_m<<<(NN + MROWS - 1) / MROWS, 256, 0, stream>>>(
        xc, aggrc, ycomp,
        wfmt + (size_t)(c * 2 + 0) * 2 * 65536,
        wfmt + (size_t)(c * 2 + 1) * 2 * 65536,
        b1 + (size_t)c * DD, b2 + (size_t)c * DD,
        nlist + c * NN, ncount + c, eps + c,
        gd1 + c * DD, gd2 + c * DD);
    k_bnstats_m<<<1, DD, 0, stream>>>(gx1 + c * DD, gx2 + c * DD,
                                      gd1 + c * DD, gd2 + c * DD,
                                      gamma + (size_t)c * DD, beta + (size_t)c * DD,
                                      scale, shift);
    k_bnapply<<<1024, 256, 0, stream>>>(
        xc, ycomp, pcl, scale, shift, xcur, x16,
        gx1 + (c + 1) * DD, gx2 + (c + 1) * DD,
        x_in, out, c, (c == CC - 1) ? 1 : 0);
  }
}